// Round 21
// baseline (454.269 us; speedup 1.0000x reference)
//
#include <hip/hip_runtime.h>
#include <stdint.h>

#define DM 2048
#define NH 16
#define HD 128
#define BB 4
#define SS 2048
#define BS (BB*SS)      // 8192 rows
#define NQKV (3*DM)     // 6144
// softmax scale folded into Q at GEMM epilogue, in exp2 domain:
// 1/sqrt(128) * log2(e)
#define SCQ 0.12751744565f

typedef __bf16 bf16_t;
typedef __attribute__((ext_vector_type(8))) __bf16 bf16x8;
typedef __attribute__((ext_vector_type(4))) float f32x4;
typedef __attribute__((ext_vector_type(16))) float f32x16;
typedef __attribute__((ext_vector_type(4))) float float4v;
typedef __attribute__((ext_vector_type(4))) unsigned int uint4v;
typedef __attribute__((ext_vector_type(4))) unsigned short ushort4v;
typedef __attribute__((ext_vector_type(8))) unsigned short ushort8;

__device__ __forceinline__ unsigned short f2bf(float f) {
  unsigned u = __float_as_uint(f);
  u += 0x7fffu + ((u >> 16) & 1u);
  return (unsigned short)(u >> 16);
}

// async global->LDS, 16B per lane; dest = (wave-uniform) l + lane*16
__device__ __forceinline__ void gl16(const void* g, void* l) {
  __builtin_amdgcn_global_load_lds(
      (const __attribute__((address_space(1))) unsigned int*)(unsigned long long)g,
      (__attribute__((address_space(3))) unsigned int*)(unsigned int)(unsigned long long)l,
      16, 0, 0);
}

// ---------------- fused fp32 -> bf16 conversion for all 5 inputs ----------
__global__ void conv_all(const float* __restrict__ x,  const float* __restrict__ wq,
                         const float* __restrict__ wk, const float* __restrict__ wv,
                         const float* __restrict__ wo,
                         unsigned short* __restrict__ xbf,
                         unsigned short* __restrict__ wqkv,
                         unsigned short* __restrict__ wobf) {
  const int NX = BS * DM / 4;    // 4M float4 units
  const int NW = DM * DM / 4;    // 1M
  int i = blockIdx.x * blockDim.x + threadIdx.x;
  int stride = gridDim.x * blockDim.x;
  for (; i < NX + 4 * NW; i += stride) {
    const float4v* src;
    ushort4v* dst;
    if (i < NX)               { src = (const float4v*)x  + i;            dst = (ushort4v*)xbf + i; }
    else if (i < NX + NW)     { int j = i - NX;          src = (const float4v*)wq + j; dst = (ushort4v*)wqkv + j; }
    else if (i < NX + 2 * NW) { int j = i - NX - NW;     src = (const float4v*)wk + j; dst = (ushort4v*)wqkv + NW + j; }
    else if (i < NX + 3 * NW) { int j = i - NX - 2 * NW; src = (const float4v*)wv + j; dst = (ushort4v*)wqkv + 2 * NW + j; }
    else                      { int j = i - NX - 3 * NW; src = (const float4v*)wo + j; dst = (ushort4v*)wobf + j; }
    float4v v = *src;
    ushort4v o;
    o.x = f2bf(v.x); o.y = f2bf(v.y); o.z = f2bf(v.z); o.w = f2bf(v.w);
    *dst = o;
  }
}

// ---------------- V transpose: fp32 [bh][s][d] -> bf16 [bh][d][s] ----------
__global__ void vtrans(const float* __restrict__ vf, bf16_t* __restrict__ vt) {
  __shared__ unsigned short T[128 * 64];  // [d][s-chunk] swizzled, 16KB
  const int t = threadIdx.x;
  const int s0 = blockIdx.x * 64;
  const int bh = blockIdx.y;
  const size_t in_off = (size_t)bh * SS * HD;
  const int sr = t >> 5, c4 = t & 31;
#pragma unroll
  for (int j = 0; j < 8; ++j) {
    int s = j * 8 + sr;
    float4v v = *(const float4v*)(vf + in_off + (size_t)(s0 + s) * HD + c4 * 4);
#pragma unroll
    for (int q = 0; q < 4; ++q) {
      int d = c4 * 4 + q;
      int bc = s * 2;
      int byt = d * 128 + ((((bc >> 4) ^ (d & 7)) << 4) | (bc & 15));
      *(unsigned short*)((char*)T + byt) = f2bf(v[q]);
    }
  }
  __syncthreads();
  const int dr = t >> 3, c8 = t & 7;
  unsigned short* out = (unsigned short*)vt + (size_t)bh * HD * SS;
#pragma unroll
  for (int j = 0; j < 4; ++j) {
    int d = j * 32 + dr;
    ushort8 val = *(const ushort8*)((char*)T + d * 128 + ((c8 ^ (d & 7)) << 4));
    *(ushort8*)(out + (size_t)d * SS + s0 + c8 * 8) = val;
  }
}

// ---------------- GEMM: 128x128, BK=64, dbuf+gl16, 1 bar/tile, 8 waves ----
// r20 winner: 993 TF, MfmaUtil 48%, occ 41% (16 waves/CU).
// MODE 1: QKV scatter epilogue (q bf16*SCQ; k bf16 + k fp32; v fp32).
// MODE 0: plain fp32 C row-major [M,N].
template<int MODE>
__global__ __launch_bounds__(512)
void gemm64w(const bf16_t* __restrict__ A, const bf16_t* __restrict__ Bm,
             const int K, const int N,
             float* __restrict__ Cf,
             bf16_t* __restrict__ qbf, bf16_t* __restrict__ kbt,
             float* __restrict__ kf, float* __restrict__ vf) {
  __shared__ bf16_t As[2][128 * 64];
  __shared__ bf16_t Bs[2][128 * 64];
  const int t = threadIdx.x;
  const int w = t >> 6, lane = t & 63;
  const int wm = (w >> 2) * 64, wn = (w & 3) * 32;
  const int row0 = blockIdx.x * 128, col0 = blockIdx.y * 128;
  const int fr = lane & 15, fq = lane >> 4;
  const int NT = K >> 6;   // 32 tiles

  const bf16_t* Asrc[2];
  const bf16_t* Bsrc[2];
  int dst[2];
#pragma unroll
  for (int j = 0; j < 2; ++j) {
    int u = j * 512 + t, r = u >> 3, c = u & 7;   // row 0..127, 16B chunk 0..7
    Asrc[j] = A + (size_t)(row0 + r) * K + ((c ^ ((r >> 1) & 7)) * 8);
    Bsrc[j] = Bm + (size_t)(col0 + r) * K + ((c ^ ((r >> 1) & 7)) * 8);
    dst[j] = u * 16;
  }

  f32x4 acc[4][2] = {};

#pragma unroll
  for (int j = 0; j < 2; ++j) {
    gl16(Asrc[j], (char*)(&As[0][0]) + dst[j]);
    gl16(Bsrc[j], (char*)(&Bs[0][0]) + dst[j]);
  }

  for (int T = 0; T < NT; ++T) {
    const int cur = T & 1;
    __syncthreads();   // vmcnt(0) drain: tile T staged; buf[cur^1] readers done

    if (T + 1 < NT) {
      const size_t ko = (size_t)(T + 1) * 64;
#pragma unroll
      for (int j = 0; j < 2; ++j) {
        gl16(Asrc[j] + ko, (char*)(&As[cur ^ 1][0]) + dst[j]);
        gl16(Bsrc[j] + ko, (char*)(&Bs[cur ^ 1][0]) + dst[j]);
      }
    }

    const bf16_t* al = &As[cur][0];
    const bf16_t* bl = &Bs[cur][0];
#pragma unroll
    for (int ks = 0; ks < 2; ++ks) {
      bf16x8 af[4], bfv[2];
#pragma unroll
      for (int f = 0; f < 4; ++f) {
        int ra = wm + f * 16 + fr;
        af[f] = *(const bf16x8*)(al + ra * 64 + (((fq + ks * 4) ^ ((ra >> 1) & 7)) * 8));
      }
#pragma unroll
      for (int n = 0; n < 2; ++n) {
        int rb = wn + n * 16 + fr;
        bfv[n] = *(const bf16x8*)(bl + rb * 64 + (((fq + ks * 4) ^ ((rb >> 1) & 7)) * 8));
      }
#pragma unroll
      for (int i = 0; i < 4; ++i)
#pragma unroll
        for (int jn = 0; jn < 2; ++jn)
          acc[i][jn] = __builtin_amdgcn_mfma_f32_16x16x32_bf16(af[i], bfv[jn], acc[i][jn], 0, 0, 0);
    }
  }

  // epilogue: C/D layout col=lane&15, row=(lane>>4)*4+reg
#pragma unroll
  for (int i = 0; i < 4; ++i) {
#pragma unroll
    for (int jn = 0; jn < 2; ++jn) {
#pragma unroll
      for (int r = 0; r < 4; ++r) {
        int m = row0 + wm + i * 16 + fq * 4 + r;
        int n = col0 + wn + jn * 16 + fr;
        float v = acc[i][jn][r];
        if (MODE == 0) {
          Cf[(size_t)m * N + n] = v;
        } else {
          int b = m >> 11, s = m & 2047;
          if (n < DM) {
            int h = n >> 7, d = n & 127;
            qbf[(((size_t)(b * NH + h)) * SS + s) * HD + d] = (bf16_t)(v * SCQ);
          } else if (n < 2 * DM) {
            int nn = n - DM, h = nn >> 7, d = nn & 127;
            size_t o = (((size_t)(b * NH + h)) * SS + s) * HD + d;
            kbt[o] = (bf16_t)v;
            kf[o] = v;
          } else {
            int nn = n - 2 * DM, h = nn >> 7, d = nn & 127;
            vf[(((size_t)(b * NH + h)) * SS + s) * HD + d] = v;
          }
        }
      }
    }
  }
}

// ---------------- causal flash attention v6: QB=256, 8 waves --------------
// Barrier-amortization applied to attn (the r15-r20 GEMM mechanism): per bh,
// 8 blocks x ~18 tile-iters instead of 16 x ~17 -> ~half the barrier+staging
// events for identical MFMA work; K/V staging per q-row halves.  Schedule,
// per-wave state (32 q/wave, swapped 32x32 QK^T, permlane P->A), LDS (64KB)
// all unchanged from attn_fwd5.  512 blocks (64 bh x 8 qtiles), XCD-chunked,
// big-first; mask when kt >= 4*qt; nt = 4*qt+4.
__global__ __launch_bounds__(512)
void attn_fwd6(const bf16_t* __restrict__ qbf, const bf16_t* __restrict__ kbf,
               const bf16_t* __restrict__ vt, bf16_t* __restrict__ aout) {
  __shared__ bf16_t Ks[2][64 * 128];   // [row s][256B = 16 chunks], chunk ^= (row&15)
  __shared__ bf16_t Vs[2][64 * 128];   // row R: d = 2R + (c>>3), k8 = c&7; chunk ^= (R&15)
  const int t = threadIdx.x, w = t >> 6, lane = t & 63;
  const int l31 = lane & 31, hi = lane >> 5;
  const int orig = blockIdx.x;
  const int wg = (orig & 7) * 64 + (orig >> 3);    // XCD-chunked, bijective (512%8==0)
  const int bh = wg >> 3;
  const int qt = 7 - (wg & 7);                     // big-first within bh
  const int q0 = qt * 256;
  const int nt = 4 * qt + 4;
  const size_t bh_off = (size_t)bh * SS * HD;
  const char* kbase = (const char*)(kbf + bh_off);
  const char* vbase = (const char*)(vt + bh_off);

  // per-wave staging: 2 gl16 for K + 2 for V (8 waves cover the 16KB tile)
  const char* ksrc[2];
  const char* vsrc[2];
#pragma unroll
  for (int i = 0; i < 2; ++i) {
    int r = (w * 2 + i) * 4 + (lane >> 4);
    int c = (lane & 15) ^ (r & 15);
    ksrc[i] = kbase + r * 256 + c * 16;
    int d = 2 * r + (c >> 3);
    vsrc[i] = vbase + (size_t)d * (SS * 2) + (c & 7) * 16;
  }

  bf16x8 qfr[8];
  {
    const char* qrow = (const char*)(qbf + bh_off + (size_t)(q0 + w * 32 + l31) * HD);
#pragma unroll
    for (int ds = 0; ds < 8; ++ds)
      qfr[ds] = *(const bf16x8*)(qrow + ds * 32 + hi * 16);
  }

#pragma unroll
  for (int i = 0; i < 2; ++i) {
    gl16(ksrc[i], (char*)(&Ks[0][0]) + (w * 2 + i) * 1024);
    gl16(vsrc[i], (char*)(&Vs[0][0]) + (w * 2 + i) * 1024);
    ksrc[i] += 16384;
    vsrc[i] += 128;
  }

  float mrow = -3.0e38f, lrow = 0.f;
  f32x16 accO[4] = {};

  // In-reg P->A-frag via permlane32_swap:
  auto make_pa = [&](const f32x16& sv, bf16x8& paA, bf16x8& paB) {
    unsigned W[8];
#pragma unroll
    for (int m = 0; m < 8; ++m) {
      float lo = sv[2 * m], hh = sv[2 * m + 1];
      asm("v_cvt_pk_bf16_f32 %0, %1, %2" : "=v"(W[m]) : "v"(lo), "v"(hh));
    }
    asm volatile("v_permlane32_swap_b32 %0, %1" : "+v"(W[0]), "+v"(W[2]));
    asm volatile("v_permlane32_swap_b32 %0, %1" : "+v"(W[1]), "+v"(W[3]));
    asm volatile("v_permlane32_swap_b32 %0, %1" : "+v"(W[4]), "+v"(W[6]));
    asm volatile("v_permlane32_swap_b32 %0, %1" : "+v"(W[5]), "+v"(W[7]));
    uint4v u0; u0.x = W[0]; u0.y = W[1]; u0.z = W[2]; u0.w = W[3];
    paA = __builtin_bit_cast(bf16x8, u0);
    uint4v u1; u1.x = W[4]; u1.y = W[5]; u1.z = W[6]; u1.w = W[7];
    paB = __builtin_bit_cast(bf16x8, u1);
  };

  for (int kt = 0; kt < nt; ++kt) {
    const int cur = kt & 1;
    __syncthreads();   // vmcnt(0) drain: tile kt staged; prev readers done

    if (kt + 1 < nt) {
#pragma unroll
      for (int i = 0; i < 2; ++i) {
        gl16(ksrc[i], (char*)(&Ks[cur ^ 1][0]) + (w * 2 + i) * 1024);
        gl16(vsrc[i], (char*)(&Vs[cur ^ 1][0]) + (w * 2 + i) * 1024);
        ksrc[i] += 16384;
        vsrc[i] += 128;
      }
    }

    // swapped QK^T
    const char* kl = (const char*)&Ks[cur][0];
    f32x16 s0 = {}, s1 = {};
    const int rck = l31 & 15;
    __builtin_amdgcn_s_setprio(1);
#pragma unroll
    for (int ds = 0; ds < 8; ++ds) {
      int ch = ((2 * ds + hi) ^ rck) << 4;
      bf16x8 kf0 = *(const bf16x8*)(kl + l31 * 256 + ch);
      s0 = __builtin_amdgcn_mfma_f32_32x32x16_bf16(kf0, qfr[ds], s0, 0, 0, 0);
      bf16x8 kf1 = *(const bf16x8*)(kl + (32 + l31) * 256 + ch);
      s1 = __builtin_amdgcn_mfma_f32_32x32x16_bf16(kf1, qfr[ds], s1, 0, 0, 0);
    }
    __builtin_amdgcn_s_setprio(0);

    // mask + online softmax (exp2 domain, defer-max)
    const int kv0 = kt * 64;
    if (kt >= 4 * qt) {
      const int qg = q0 + w * 32 + l31;
#pragma unroll
      for (int r = 0; r < 16; ++r) {
        int klo = kv0 + (r & 3) + 8 * (r >> 2) + 4 * hi;
        if (klo > qg) s0[r] = -3.0e38f;
        if (klo + 32 > qg) s1[r] = -3.0e38f;
      }
    }
    float rm = s0[0];
#pragma unroll
    for (int r = 1; r < 16; ++r) rm = fmaxf(rm, s0[r]);
#pragma unroll
    for (int r = 0; r < 16; ++r) rm = fmaxf(rm, s1[r]);
    rm = fmaxf(rm, __shfl_xor(rm, 32, 64));
    if (__ballot(rm > mrow + 8.0f)) {
      float mnew = fmaxf(mrow, rm);
      float fct = __builtin_amdgcn_exp2f(mrow - mnew);
      mrow = mnew;
      lrow *= fct;
#pragma unroll
      for (int r = 0; r < 16; ++r) {
        float f = __shfl(fct, (r & 3) + 8 * (r >> 2) + 4 * hi, 64);
        accO[0][r] *= f; accO[1][r] *= f; accO[2][r] *= f; accO[3][r] *= f;
      }
    }
    float ss = 0.f;
#pragma unroll
    for (int r = 0; r < 16; ++r) { float p = __builtin_amdgcn_exp2f(s0[r] - mrow); s0[r] = p; ss += p; }
#pragma unroll
    for (int r = 0; r < 16; ++r) { float p = __builtin_amdgcn_exp2f(s1[r] - mrow); s1[r] = p; ss += p; }
    ss += __shfl_xor(ss, 32, 64);
    lrow += ss;

    bf16x8 pa00, pa01, pa10, pa11;
    make_pa(s0, pa00, pa01);
    make_pa(s1, pa10, pa11);

    // PV
    const char* vl = (const char*)&Vs[cur][0];
    __builtin_amdgcn_s_setprio(1);
#pragma unroll
    for (int dt = 0; dt < 4; ++dt) {
      int R = dt * 16 + (l31 >> 1);
      int cb = (l31 & 1) << 3;
      int rx = R & 15;
      bf16x8 v00 = *(const bf16x8*)(vl + R * 256 + (((cb + 0 + hi) ^ rx) << 4));
      accO[dt] = __builtin_amdgcn_mfma_f32_32x32x16_bf16(pa00, v00, accO[dt], 0, 0, 0);
      bf16x8 v01 = *(const bf16x8*)(vl + R * 256 + (((cb + 2 + hi) ^ rx) << 4));
      accO[dt] = __builtin_amdgcn_mfma_f32_32x32x16_bf16(pa01, v01, accO[dt], 0, 0, 0);
      bf16x8 v10 = *(const bf16x8*)(vl + R * 256 + (((cb + 4 + hi) ^ rx) << 4));
      accO[dt] = __builtin_amdgcn_mfma_f32_32x32x16_bf16(pa10, v10, accO[dt], 0, 0, 0);
      bf16x8 v11 = *(const bf16x8*)(vl + R * 256 + (((cb + 6 + hi) ^ rx) << 4));
      accO[dt] = __builtin_amdgcn_mfma_f32_32x32x16_bf16(pa11, v11, accO[dt], 0, 0, 0);
    }
    __builtin_amdgcn_s_setprio(0);
  }

  // normalize + write attn out as [b, s, h*128+d] bf16
  const int b = bh >> 4, h = bh & 15;
#pragma unroll
  for (int r = 0; r < 16; ++r) {
    int qr = (r & 3) + 8 * (r >> 2) + 4 * hi;
    float inv = __builtin_amdgcn_rcpf(__shfl(lrow, qr, 64));
    int srow = q0 + w * 32 + qr;
    bf16_t* orow = aout + ((size_t)(b * SS + srow)) * DM + h * HD + l31;
    orow[0]  = (bf16_t)(accO[0][r] * inv);
    orow[32] = (bf16_t)(accO[1][r] * inv);
    orow[64] = (bf16_t)(accO[2][r] * inv);
    orow[96] = (bf16_t)(accO[3][r] * inv);
  }
}

// ---------------- launch ---------------------------------------------------
extern "C" void kernel_launch(void* const* d_in, const int* in_sizes, int n_in,
                              void* d_out, int out_size, void* d_ws, size_t ws_size,
                              hipStream_t stream) {
  (void)in_sizes; (void)n_in; (void)out_size; (void)ws_size;
  const float* x  = (const float*)d_in[0];
  const float* Wq = (const float*)d_in[1];
  const float* Wk = (const float*)d_in[2];
  const float* Wv = (const float*)d_in[3];
  const float* Wo = (const float*)d_in[4];

  float* y  = (float*)d_out;                       // [8192, 2048] fp32
  float* kf = y + (size_t)BS * DM;                 // fp32 [b,h,s,d] (output)
  float* vf = kf + (size_t)BS * DM;                // fp32 [b,h,s,d] (output)

  // ws (96MB):
  //  [0,32M)  xbf (conv->gemm1), then abf (attn out -> out-proj)
  //  [32,64M) qbf (gemm1->attn)
  //  [64,88M) wqkv (conv->gemm1); [88,96M) wobf (conv->gemm0)
  // d_out y region doubles as: kbt bf16 [0,32M of y), vtb bf16 V^T [32,64M)
  char* ws = (char*)d_ws;
  bf16_t* xbf  = (bf16_t*)ws;
  bf16_t* abf  = xbf;
  bf16_t* qbf  = (bf16_t*)(ws + (size_t)32 * 1024 * 1024);
  bf16_t* wqkv = (bf16_t*)(ws + (size_t)64 * 1024 * 1024);
  bf16_t* wobf = (bf16_t*)(ws + (size_t)88 * 1024 * 1024);
  bf16_t* kbt  = (bf16_t*)y;
  bf16_t* vtb  = (bf16_t*)((char*)y + (size_t)32 * 1024 * 1024);

  conv_all<<<2048, 256, 0, stream>>>(x, Wq, Wk, Wv, Wo,
                                     (unsigned short*)xbf, (unsigned short*)wqkv,
                                     (unsigned short*)wobf);

  // QKV projection: 2D grid (64 M x 48 N), default round-robin XCD order
  gemm64w<1><<<dim3(BS / 128, NQKV / 128), 512, 0, stream>>>(
      xbf, wqkv, DM, NQKV, nullptr, qbf, kbt, kf, vf);

  vtrans<<<dim3(SS / 64, BB * NH), 256, 0, stream>>>(vf, vtb);

  // attention: 512 blocks (64 bh x 8 qtiles), QB=256, 8 waves
  attn_fwd6<<<512, 512, 0, stream>>>(qbf, kbt, vtb, abf);

  // out-proj: 2D grid (64 M x 16 N), same structure
  gemm64w<0><<<dim3(BS / 128, DM / 128), 512, 0, stream>>>(
      abf, wobf, DM, DM, y, nullptr, nullptr, nullptr, nullptr);
}

// Round 22
// 442.596 us; speedup vs baseline: 1.0264x; 1.0264x over previous
//
#include <hip/hip_runtime.h>
#include <stdint.h>

#define DM 2048
#define NH 16
#define HD 128
#define BB 4
#define SS 2048
#define BS (BB*SS)      // 8192 rows
#define NQKV (3*DM)     // 6144
// softmax scale folded into Q at GEMM epilogue, in exp2 domain:
// 1/sqrt(128) * log2(e)
#define SCQ 0.12751744565f

typedef __bf16 bf16_t;
typedef __attribute__((ext_vector_type(8))) __bf16 bf16x8;
typedef __attribute__((ext_vector_type(4))) float f32x4;
typedef __attribute__((ext_vector_type(16))) float f32x16;
typedef __attribute__((ext_vector_type(4))) float float4v;
typedef __attribute__((ext_vector_type(4))) unsigned int uint4v;
typedef __attribute__((ext_vector_type(4))) unsigned short ushort4v;
typedef __attribute__((ext_vector_type(8))) unsigned short ushort8;

__device__ __forceinline__ unsigned short f2bf(float f) {
  unsigned u = __float_as_uint(f);
  u += 0x7fffu + ((u >> 16) & 1u);
  return (unsigned short)(u >> 16);
}

// async global->LDS, 16B per lane; dest = (wave-uniform) l + lane*16
__device__ __forceinline__ void gl16(const void* g, void* l) {
  __builtin_amdgcn_global_load_lds(
      (const __attribute__((address_space(1))) unsigned int*)(unsigned long long)g,
      (__attribute__((address_space(3))) unsigned int*)(unsigned int)(unsigned long long)l,
      16, 0, 0);
}

// ---------------- fused fp32 -> bf16 conversion for all 5 inputs ----------
__global__ void conv_all(const float* __restrict__ x,  const float* __restrict__ wq,
                         const float* __restrict__ wk, const float* __restrict__ wv,
                         const float* __restrict__ wo,
                         unsigned short* __restrict__ xbf,
                         unsigned short* __restrict__ wqkv,
                         unsigned short* __restrict__ wobf) {
  const int NX = BS * DM / 4;    // 4M float4 units
  const int NW = DM * DM / 4;    // 1M
  int i = blockIdx.x * blockDim.x + threadIdx.x;
  int stride = gridDim.x * blockDim.x;
  for (; i < NX + 4 * NW; i += stride) {
    const float4v* src;
    ushort4v* dst;
    if (i < NX)               { src = (const float4v*)x  + i;            dst = (ushort4v*)xbf + i; }
    else if (i < NX + NW)     { int j = i - NX;          src = (const float4v*)wq + j; dst = (ushort4v*)wqkv + j; }
    else if (i < NX + 2 * NW) { int j = i - NX - NW;     src = (const float4v*)wk + j; dst = (ushort4v*)wqkv + NW + j; }
    else if (i < NX + 3 * NW) { int j = i - NX - 2 * NW; src = (const float4v*)wv + j; dst = (ushort4v*)wqkv + 2 * NW + j; }
    else                      { int j = i - NX - 3 * NW; src = (const float4v*)wo + j; dst = (ushort4v*)wobf + j; }
    float4v v = *src;
    ushort4v o;
    o.x = f2bf(v.x); o.y = f2bf(v.y); o.z = f2bf(v.z); o.w = f2bf(v.w);
    *dst = o;
  }
}

// ---------------- V transpose: fp32 [bh][s][d] -> bf16 [bh][d][s] ----------
__global__ void vtrans(const float* __restrict__ vf, bf16_t* __restrict__ vt) {
  __shared__ unsigned short T[128 * 64];  // [d][s-chunk] swizzled, 16KB
  const int t = threadIdx.x;
  const int s0 = blockIdx.x * 64;
  const int bh = blockIdx.y;
  const size_t in_off = (size_t)bh * SS * HD;
  const int sr = t >> 5, c4 = t & 31;
#pragma unroll
  for (int j = 0; j < 8; ++j) {
    int s = j * 8 + sr;
    float4v v = *(const float4v*)(vf + in_off + (size_t)(s0 + s) * HD + c4 * 4);
#pragma unroll
    for (int q = 0; q < 4; ++q) {
      int d = c4 * 4 + q;
      int bc = s * 2;
      int byt = d * 128 + ((((bc >> 4) ^ (d & 7)) << 4) | (bc & 15));
      *(unsigned short*)((char*)T + byt) = f2bf(v[q]);
    }
  }
  __syncthreads();
  const int dr = t >> 3, c8 = t & 7;
  unsigned short* out = (unsigned short*)vt + (size_t)bh * HD * SS;
#pragma unroll
  for (int j = 0; j < 4; ++j) {
    int d = j * 32 + dr;
    ushort8 val = *(const ushort8*)((char*)T + d * 128 + ((c8 ^ (d & 7)) << 4));
    *(ushort8*)(out + (size_t)d * SS + s0 + c8 * 8) = val;
  }
}

// ---------------- GEMM: 128x128, BK=64, dbuf+gl16, 1 bar/tile, 8 waves ----
// r20 winner: 993 TF, MfmaUtil 48%, occ 41% (16 waves/CU).  Barrier-
// amortization series: 2bar/BK32=775, 2bar/BK64=905, 1bar/BK64-4w=948,
// 1bar/BK64-8w=993 TF.
// MODE 1: QKV scatter epilogue (q bf16*SCQ; k bf16 + k fp32; v fp32).
// MODE 0: plain fp32 C row-major [M,N].
template<int MODE>
__global__ __launch_bounds__(512)
void gemm64w(const bf16_t* __restrict__ A, const bf16_t* __restrict__ Bm,
             const int K, const int N,
             float* __restrict__ Cf,
             bf16_t* __restrict__ qbf, bf16_t* __restrict__ kbt,
             float* __restrict__ kf, float* __restrict__ vf) {
  __shared__ bf16_t As[2][128 * 64];
  __shared__ bf16_t Bs[2][128 * 64];
  const int t = threadIdx.x;
  const int w = t >> 6, lane = t & 63;
  const int wm = (w >> 2) * 64, wn = (w & 3) * 32;
  const int row0 = blockIdx.x * 128, col0 = blockIdx.y * 128;
  const int fr = lane & 15, fq = lane >> 4;
  const int NT = K >> 6;   // 32 tiles

  const bf16_t* Asrc[2];
  const bf16_t* Bsrc[2];
  int dst[2];
#pragma unroll
  for (int j = 0; j < 2; ++j) {
    int u = j * 512 + t, r = u >> 3, c = u & 7;   // row 0..127, 16B chunk 0..7
    Asrc[j] = A + (size_t)(row0 + r) * K + ((c ^ ((r >> 1) & 7)) * 8);
    Bsrc[j] = Bm + (size_t)(col0 + r) * K + ((c ^ ((r >> 1) & 7)) * 8);
    dst[j] = u * 16;
  }

  f32x4 acc[4][2] = {};

#pragma unroll
  for (int j = 0; j < 2; ++j) {
    gl16(Asrc[j], (char*)(&As[0][0]) + dst[j]);
    gl16(Bsrc[j], (char*)(&Bs[0][0]) + dst[j]);
  }

  for (int T = 0; T < NT; ++T) {
    const int cur = T & 1;
    __syncthreads();   // vmcnt(0) drain: tile T staged; buf[cur^1] readers done

    if (T + 1 < NT) {
      const size_t ko = (size_t)(T + 1) * 64;
#pragma unroll
      for (int j = 0; j < 2; ++j) {
        gl16(Asrc[j] + ko, (char*)(&As[cur ^ 1][0]) + dst[j]);
        gl16(Bsrc[j] + ko, (char*)(&Bs[cur ^ 1][0]) + dst[j]);
      }
    }

    const bf16_t* al = &As[cur][0];
    const bf16_t* bl = &Bs[cur][0];
#pragma unroll
    for (int ks = 0; ks < 2; ++ks) {
      bf16x8 af[4], bfv[2];
#pragma unroll
      for (int f = 0; f < 4; ++f) {
        int ra = wm + f * 16 + fr;
        af[f] = *(const bf16x8*)(al + ra * 64 + (((fq + ks * 4) ^ ((ra >> 1) & 7)) * 8));
      }
#pragma unroll
      for (int n = 0; n < 2; ++n) {
        int rb = wn + n * 16 + fr;
        bfv[n] = *(const bf16x8*)(bl + rb * 64 + (((fq + ks * 4) ^ ((rb >> 1) & 7)) * 8));
      }
#pragma unroll
      for (int i = 0; i < 4; ++i)
#pragma unroll
        for (int jn = 0; jn < 2; ++jn)
          acc[i][jn] = __builtin_amdgcn_mfma_f32_16x16x32_bf16(af[i], bfv[jn], acc[i][jn], 0, 0, 0);
    }
  }

  // epilogue: C/D layout col=lane&15, row=(lane>>4)*4+reg
#pragma unroll
  for (int i = 0; i < 4; ++i) {
#pragma unroll
    for (int jn = 0; jn < 2; ++jn) {
#pragma unroll
      for (int r = 0; r < 4; ++r) {
        int m = row0 + wm + i * 16 + fq * 4 + r;
        int n = col0 + wn + jn * 16 + fr;
        float v = acc[i][jn][r];
        if (MODE == 0) {
          Cf[(size_t)m * N + n] = v;
        } else {
          int b = m >> 11, s = m & 2047;
          if (n < DM) {
            int h = n >> 7, d = n & 127;
            qbf[(((size_t)(b * NH + h)) * SS + s) * HD + d] = (bf16_t)(v * SCQ);
          } else if (n < 2 * DM) {
            int nn = n - DM, h = nn >> 7, d = nn & 127;
            size_t o = (((size_t)(b * NH + h)) * SS + s) * HD + d;
            kbt[o] = (bf16_t)v;
            kf[o] = v;
          } else {
            int nn = n - 2 * DM, h = nn >> 7, d = nn & 127;
            vf[(((size_t)(b * NH + h)) * SS + s) * HD + d] = v;
          }
        }
      }
    }
  }
}

// ---------------- causal flash attention v5 --------------------------------
// QB=128, 4 waves (r20/session-best form; r21's QB=256/8-wave regressed:
// load-balance + staging-parallelism loss outweighed barrier savings).
// Swapped QK^T (P lane-local); P->A-frag via cvt_pk + permlane32_swap.
// K/V^T staged bf16 via global_load_lds (pre-swizzled source), dbuf;
// barrier -> issue next tile gl16 -> compute cur.
__global__ __launch_bounds__(256, 2)
void attn_fwd5(const bf16_t* __restrict__ qbf, const bf16_t* __restrict__ kbf,
               const bf16_t* __restrict__ vt, bf16_t* __restrict__ aout) {
  __shared__ bf16_t Ks[2][64 * 128];   // [row s][256B = 16 chunks], chunk ^= (row&15)
  __shared__ bf16_t Vs[2][64 * 128];   // row R: d = 2R + (c>>3), k8 = c&7; chunk ^= (R&15)
  const int t = threadIdx.x, w = t >> 6, lane = t & 63;
  const int l31 = lane & 31, hi = lane >> 5;
  const int orig = blockIdx.x;
  const int wg = (orig & 7) * 128 + (orig >> 3);   // XCD-chunked, bijective
  const int bh = wg >> 4;
  const int qt = 15 - (wg & 15);                   // big-first within bh
  const int q0 = qt * 128;
  const int nt = 2 * qt + 2;
  const size_t bh_off = (size_t)bh * SS * HD;
  const char* kbase = (const char*)(kbf + bh_off);
  const char* vbase = (const char*)(vt + bh_off);

  const char* ksrc[4];
  const char* vsrc[4];
#pragma unroll
  for (int i = 0; i < 4; ++i) {
    int r = (w * 4 + i) * 4 + (lane >> 4);
    int c = (lane & 15) ^ (r & 15);
    ksrc[i] = kbase + r * 256 + c * 16;
    int d = 2 * r + (c >> 3);
    vsrc[i] = vbase + (size_t)d * (SS * 2) + (c & 7) * 16;
  }

  bf16x8 qfr[8];
  {
    const char* qrow = (const char*)(qbf + bh_off + (size_t)(q0 + w * 32 + l31) * HD);
#pragma unroll
    for (int ds = 0; ds < 8; ++ds)
      qfr[ds] = *(const bf16x8*)(qrow + ds * 32 + hi * 16);
  }

#pragma unroll
  for (int i = 0; i < 4; ++i) {
    gl16(ksrc[i], (char*)(&Ks[0][0]) + (w * 4 + i) * 1024);
    gl16(vsrc[i], (char*)(&Vs[0][0]) + (w * 4 + i) * 1024);
    ksrc[i] += 16384;
    vsrc[i] += 128;
  }

  float mrow = -3.0e38f, lrow = 0.f;
  f32x16 accO[4] = {};

  // In-reg P->A-frag via permlane32_swap:
  auto make_pa = [&](const f32x16& sv, bf16x8& paA, bf16x8& paB) {
    unsigned W[8];
#pragma unroll
    for (int m = 0; m < 8; ++m) {
      float lo = sv[2 * m], hh = sv[2 * m + 1];
      asm("v_cvt_pk_bf16_f32 %0, %1, %2" : "=v"(W[m]) : "v"(lo), "v"(hh));
    }
    asm volatile("v_permlane32_swap_b32 %0, %1" : "+v"(W[0]), "+v"(W[2]));
    asm volatile("v_permlane32_swap_b32 %0, %1" : "+v"(W[1]), "+v"(W[3]));
    asm volatile("v_permlane32_swap_b32 %0, %1" : "+v"(W[4]), "+v"(W[6]));
    asm volatile("v_permlane32_swap_b32 %0, %1" : "+v"(W[5]), "+v"(W[7]));
    uint4v u0; u0.x = W[0]; u0.y = W[1]; u0.z = W[2]; u0.w = W[3];
    paA = __builtin_bit_cast(bf16x8, u0);
    uint4v u1; u1.x = W[4]; u1.y = W[5]; u1.z = W[6]; u1.w = W[7];
    paB = __builtin_bit_cast(bf16x8, u1);
  };

  for (int kt = 0; kt < nt; ++kt) {
    const int cur = kt & 1;
    __syncthreads();   // vmcnt(0) drain: tile kt staged; prev readers done

    if (kt + 1 < nt) {
#pragma unroll
      for (int i = 0; i < 4; ++i) {
        gl16(ksrc[i], (char*)(&Ks[cur ^ 1][0]) + (w * 4 + i) * 1024);
        gl16(vsrc[i], (char*)(&Vs[cur ^ 1][0]) + (w * 4 + i) * 1024);
        ksrc[i] += 16384;
        vsrc[i] += 128;
      }
    }

    // swapped QK^T
    const char* kl = (const char*)&Ks[cur][0];
    f32x16 s0 = {}, s1 = {};
    const int rck = l31 & 15;
    __builtin_amdgcn_s_setprio(1);
#pragma unroll
    for (int ds = 0; ds < 8; ++ds) {
      int ch = ((2 * ds + hi) ^ rck) << 4;
      bf16x8 kf0 = *(const bf16x8*)(kl + l31 * 256 + ch);
      s0 = __builtin_amdgcn_mfma_f32_32x32x16_bf16(kf0, qfr[ds], s0, 0, 0, 0);
      bf16x8 kf1 = *(const bf16x8*)(kl + (32 + l31) * 256 + ch);
      s1 = __builtin_amdgcn_mfma_f32_32x32x16_bf16(kf1, qfr[ds], s1, 0, 0, 0);
    }
    __builtin_amdgcn_s_setprio(0);

    // mask + online softmax (exp2 domain, defer-max)
    const int kv0 = kt * 64;
    if (kt >= 2 * qt) {
      const int qg = q0 + w * 32 + l31;
#pragma unroll
      for (int r = 0; r < 16; ++r) {
        int klo = kv0 + (r & 3) + 8 * (r >> 2) + 4 * hi;
        if (klo > qg) s0[r] = -3.0e38f;
        if (klo + 32 > qg) s1[r] = -3.0e38f;
      }
    }
    float rm = s0[0];
#pragma unroll
    for (int r = 1; r < 16; ++r) rm = fmaxf(rm, s0[r]);
#pragma unroll
    for (int r = 0; r < 16; ++r) rm = fmaxf(rm, s1[r]);
    rm = fmaxf(rm, __shfl_xor(rm, 32, 64));
    if (__ballot(rm > mrow + 8.0f)) {
      float mnew = fmaxf(mrow, rm);
      float fct = __builtin_amdgcn_exp2f(mrow - mnew);
      mrow = mnew;
      lrow *= fct;
#pragma unroll
      for (int r = 0; r < 16; ++r) {
        float f = __shfl(fct, (r & 3) + 8 * (r >> 2) + 4 * hi, 64);
        accO[0][r] *= f; accO[1][r] *= f; accO[2][r] *= f; accO[3][r] *= f;
      }
    }
    float ss = 0.f;
#pragma unroll
    for (int r = 0; r < 16; ++r) { float p = __builtin_amdgcn_exp2f(s0[r] - mrow); s0[r] = p; ss += p; }
#pragma unroll
    for (int r = 0; r < 16; ++r) { float p = __builtin_amdgcn_exp2f(s1[r] - mrow); s1[r] = p; ss += p; }
    ss += __shfl_xor(ss, 32, 64);
    lrow += ss;

    bf16x8 pa00, pa01, pa10, pa11;
    make_pa(s0, pa00, pa01);
    make_pa(s1, pa10, pa11);

    // PV
    const char* vl = (const char*)&Vs[cur][0];
    __builtin_amdgcn_s_setprio(1);
#pragma unroll
    for (int dt = 0; dt < 4; ++dt) {
      int R = dt * 16 + (l31 >> 1);
      int cb = (l31 & 1) << 3;
      int rx = R & 15;
      bf16x8 v00 = *(const bf16x8*)(vl + R * 256 + (((cb + 0 + hi) ^ rx) << 4));
      accO[dt] = __builtin_amdgcn_mfma_f32_32x32x16_bf16(pa00, v00, accO[dt], 0, 0, 0);
      bf16x8 v01 = *(const bf16x8*)(vl + R * 256 + (((cb + 2 + hi) ^ rx) << 4));
      accO[dt] = __builtin_amdgcn_mfma_f32_32x32x16_bf16(pa01, v01, accO[dt], 0, 0, 0);
      bf16x8 v10 = *(const bf16x8*)(vl + R * 256 + (((cb + 4 + hi) ^ rx) << 4));
      accO[dt] = __builtin_amdgcn_mfma_f32_32x32x16_bf16(pa10, v10, accO[dt], 0, 0, 0);
      bf16x8 v11 = *(const bf16x8*)(vl + R * 256 + (((cb + 6 + hi) ^ rx) << 4));
      accO[dt] = __builtin_amdgcn_mfma_f32_32x32x16_bf16(pa11, v11, accO[dt], 0, 0, 0);
    }
    __builtin_amdgcn_s_setprio(0);
  }

  // normalize + write attn out as [b, s, h*128+d] bf16
  const int b = bh >> 4, h = bh & 15;
#pragma unroll
  for (int r = 0; r < 16; ++r) {
    int qr = (r & 3) + 8 * (r >> 2) + 4 * hi;
    float inv = __builtin_amdgcn_rcpf(__shfl(lrow, qr, 64));
    int srow = q0 + w * 32 + qr;
    bf16_t* orow = aout + ((size_t)(b * SS + srow)) * DM + h * HD + l31;
    orow[0]  = (bf16_t)(accO[0][r] * inv);
    orow[32] = (bf16_t)(accO[1][r] * inv);
    orow[64] = (bf16_t)(accO[2][r] * inv);
    orow[96] = (bf16_t)(accO[3][r] * inv);
  }
}

// ---------------- launch ---------------------------------------------------
extern "C" void kernel_launch(void* const* d_in, const int* in_sizes, int n_in,
                              void* d_out, int out_size, void* d_ws, size_t ws_size,
                              hipStream_t stream) {
  (void)in_sizes; (void)n_in; (void)out_size; (void)ws_size;
  const float* x  = (const float*)d_in[0];
  const float* Wq = (const float*)d_in[1];
  const float* Wk = (const float*)d_in[2];
  const float* Wv = (const float*)d_in[3];
  const float* Wo = (const float*)d_in[4];

  float* y  = (float*)d_out;                       // [8192, 2048] fp32
  float* kf = y + (size_t)BS * DM;                 // fp32 [b,h,s,d] (output)
  float* vf = kf + (size_t)BS * DM;                // fp32 [b,h,s,d] (output)

  // ws (96MB):
  //  [0,32M)  xbf (conv->gemm1), then abf (attn out -> out-proj)
  //  [32,64M) qbf (gemm1->attn)
  //  [64,88M) wqkv (conv->gemm1); [88,96M) wobf (conv->gemm0)
  // d_out y region doubles as: kbt bf16 [0,32M of y), vtb bf16 V^T [32,64M)
  char* ws = (char*)d_ws;
  bf16_t* xbf  = (bf16_t*)ws;
  bf16_t* abf  = xbf;
  bf16_t* qbf  = (bf16_t*)(ws + (size_t)32 * 1024 * 1024);
  bf16_t* wqkv = (bf16_t*)(ws + (size_t)64 * 1024 * 1024);
  bf16_t* wobf = (bf16_t*)(ws + (size_t)88 * 1024 * 1024);
  bf16_t* kbt  = (bf16_t*)y;
  bf16_t* vtb  = (bf16_t*)((char*)y + (size_t)32 * 1024 * 1024);

  conv_all<<<2048, 256, 0, stream>>>(x, Wq, Wk, Wv, Wo,
                                     (unsigned short*)xbf, (unsigned short*)wqkv,
                                     (unsigned short*)wobf);

  // QKV projection: 2D grid (64 M x 48 N), default round-robin XCD order
  gemm64w<1><<<dim3(BS / 128, NQKV / 128), 512, 0, stream>>>(
      xbf, wqkv, DM, NQKV, nullptr, qbf, kbt, kf, vf);

  vtrans<<<dim3(SS / 64, BB * NH), 256, 0, stream>>>(vf, vtb);

  attn_fwd5<<<1024, 256, 0, stream>>>(qbf, kbt, vtb, abf);

  // out-proj: 2D grid (64 M x 16 N), same structure
  gemm64w<0><<<dim3(BS / 128, DM / 128), 512, 0, stream>>>(
      abf, wobf, DM, DM, y, nullptr, nullptr, nullptr, nullptr);
}